// Round 3
// baseline (528.009 us; speedup 1.0000x reference)
//
#include <hip/hip_runtime.h>

typedef unsigned short u16;
typedef unsigned int u32;
typedef __attribute__((ext_vector_type(8))) short short8;
typedef __attribute__((ext_vector_type(4))) float f32x4;

#define BB 8
#define CCH 256
#define HH 64
#define WW 64
#define HP 66
#define NPOS 4096
#define KTOT 2304

// ---- ws layout (bytes) ----
#define XT_BYTES   35684352ull                 // fp32 [8][66][66][256]
#define W2R_OFF    35684352ull                 // bf16 [256][2304]
#define WOFF2_OFF  36864000ull                 // bf16 [32][2304]
#define OFFWS_OFF  37011456ull                 // fp32 [8][4096][18]
#define GOFF_OFF   39370752ull                 // int4 [8*9*4096]
#define GW_OFF     44089344ull                 // float4 [8*9*4096]
#define WS_NEED    48807936ull

__device__ __forceinline__ float bf2f(u16 u) {
    union { u32 u; float f; } v; v.u = ((u32)u) << 16; return v.f;
}
__device__ __forceinline__ u16 f2bf(float f) {
    union { float f; u32 u; } v; v.f = f;
    u32 r = v.u + 0x7FFFu + ((v.u >> 16) & 1u);
    return (u16)(r >> 16);
}
__device__ __forceinline__ u32 pk2(float a, float b) {
    return (u32)f2bf(a) | ((u32)f2bf(b) << 16);
}

// ---- K0: reorder weights (fp32 -> bf16): W2r[o][k*256+c] = w[o][c][k]; Woff2 32 rows (>=18 zero) ----
__global__ void k_prep(const float* __restrict__ w, const float* __restrict__ w_off,
                       u16* __restrict__ W2r, u16* __restrict__ Woff2) {
    int t = blockIdx.x * 256 + threadIdx.x;
    if (t < CCH * KTOT) {
        int o = t / KTOT, kk = t % KTOT, k = kk >> 8, c = kk & 255;
        W2r[t] = f2bf(w[(o * CCH + c) * 9 + k]);
    } else {
        int u = t - CCH * KTOT;   // u < 32*2304 exactly by grid sizing
        int o = u / KTOT, kk = u % KTOT, k = kk >> 8, c = kk & 255;
        Woff2[u] = (o < 18) ? f2bf(w_off[(o * CCH + c) * 9 + k]) : (u16)0;
    }
}

// ---- K0b: off_ws[b][pos][o] = b_off[o]  (bias init; k_offconv atomically accumulates) ----
__global__ void k_init(const float* __restrict__ b_off, float* __restrict__ off_ws) {
    int t = blockIdx.x * 256 + threadIdx.x;    // 589824 exactly
    off_ws[t] = b_off[t % 18];
}

// ---- K1: transpose+pad: xT[b][y+1][x+1][c] = x[b][c][y][x]; borders pre-zeroed by memset ----
__global__ __launch_bounds__(256) void k_transpose(const float* __restrict__ x, float* __restrict__ xT) {
    __shared__ __align__(16) float T[64][72];
    int b = blockIdx.z, y = blockIdx.y, c0 = blockIdx.x * 64;
    int t = threadIdx.x;
    {
        int i = t >> 2, seg = t & 3;   // channel i, 16-float x-segment
        const float* src = x + (((size_t)(b * CCH + c0 + i) * HH + y) * WW) + seg * 16;
        float4 v0 = *(const float4*)(src);
        float4 v1 = *(const float4*)(src + 4);
        float4 v2 = *(const float4*)(src + 8);
        float4 v3 = *(const float4*)(src + 12);
        *(float4*)&T[i][seg * 16]      = v0;
        *(float4*)&T[i][seg * 16 + 4]  = v1;
        *(float4*)&T[i][seg * 16 + 8]  = v2;
        *(float4*)&T[i][seg * 16 + 12] = v3;
    }
    __syncthreads();
    {
        int xc = t >> 2, cs = t & 3;   // x-position xc, 16-channel segment cs
        float* dst = xT + (((size_t)(b * HP + y + 1) * HP) + (xc + 1)) * CCH + c0 + cs * 16;
#pragma unroll
        for (int h = 0; h < 4; ++h) {
            float4 o4;
            o4.x = T[cs * 16 + h * 4 + 0][xc];
            o4.y = T[cs * 16 + h * 4 + 1][xc];
            o4.z = T[cs * 16 + h * 4 + 2][xc];
            o4.w = T[cs * 16 + h * 4 + 3][xc];
            *(float4*)(dst + h * 4) = o4;
        }
    }
}

// ---- K2: offset conv, K-split by kernel tap k9: grid (32 posTiles, 9, 8), atomicAdd epilogue ----
__global__ __launch_bounds__(256) void k_offconv(const float* __restrict__ xT,
                                                 const u16* __restrict__ Woff2,
                                                 float* __restrict__ off_ws) {
    __shared__ __align__(16) u16 As[32 * 40];
    __shared__ __align__(16) u16 Bs[128 * 40];
    int b = blockIdx.z, k9 = blockIdx.y;
    int pos0 = blockIdx.x * 128;
    int ky = k9 / 3, kx = k9 % 3;
    int t = threadIdx.x, lane = t & 63, wv = t >> 6;
    int pos_l = t & 127, jp = t >> 7;
    int posg = pos0 + pos_l, py_ = posg >> 6, px_ = posg & 63;

    f32x4 acc[2][2];
    f32x4 z = {0.f, 0.f, 0.f, 0.f};
    acc[0][0] = z; acc[0][1] = z; acc[1][0] = z; acc[1][1] = z;

    const float* brow = xT + ((size_t)((b * HP + py_ + ky) * HP) + px_ + kx) * CCH + jp * 16;

    for (int cs = 0; cs < 8; ++cs) {
        int c0 = cs * 32;
        __syncthreads();
        if (t < 128) {
            int row = t >> 2, h = t & 3;
            uint4 v = *(const uint4*)(Woff2 + row * KTOT + k9 * 256 + c0 + h * 8);
            *(uint4*)&As[row * 40 + h * 8] = v;
        }
        {
            const float* src = brow + c0;
            float4 s0 = *(const float4*)(src);
            float4 s1 = *(const float4*)(src + 4);
            float4 s2 = *(const float4*)(src + 8);
            float4 s3 = *(const float4*)(src + 12);
            uint4 d0, d1;
            d0.x = pk2(s0.x, s0.y); d0.y = pk2(s0.z, s0.w); d0.z = pk2(s1.x, s1.y); d0.w = pk2(s1.z, s1.w);
            d1.x = pk2(s2.x, s2.y); d1.y = pk2(s2.z, s2.w); d1.z = pk2(s3.x, s3.y); d1.w = pk2(s3.z, s3.w);
            *(uint4*)&Bs[pos_l * 40 + jp * 16] = d0;
            *(uint4*)&Bs[pos_l * 40 + jp * 16 + 8] = d1;
        }
        __syncthreads();
        int q = lane >> 4, m = lane & 15;
        short8 a0 = *(const short8*)&As[m * 40 + q * 8];
        short8 a1 = *(const short8*)&As[(16 + m) * 40 + q * 8];
        short8 b0 = *(const short8*)&Bs[(wv * 32 + m) * 40 + q * 8];
        short8 b1 = *(const short8*)&Bs[(wv * 32 + 16 + m) * 40 + q * 8];
        acc[0][0] = __builtin_amdgcn_mfma_f32_16x16x32_bf16(a0, b0, acc[0][0], 0, 0, 0);
        acc[0][1] = __builtin_amdgcn_mfma_f32_16x16x32_bf16(a0, b1, acc[0][1], 0, 0, 0);
        acc[1][0] = __builtin_amdgcn_mfma_f32_16x16x32_bf16(a1, b0, acc[1][0], 0, 0, 0);
        acc[1][1] = __builtin_amdgcn_mfma_f32_16x16x32_bf16(a1, b1, acc[1][1], 0, 0, 0);
    }
    int q = lane >> 4, nn = lane & 15;
#pragma unroll
    for (int ao = 0; ao < 2; ++ao)
#pragma unroll
        for (int bn = 0; bn < 2; ++bn) {
            int pos = pos0 + wv * 32 + bn * 16 + nn;
#pragma unroll
            for (int r = 0; r < 4; ++r) {
                int o = ao * 16 + q * 4 + r;
                if (o < 18) {
                    atomicAdd(&off_ws[((size_t)(b << 12) + pos) * 18 + o], acc[ao][bn][r]);
                }
            }
        }
}

// ---- K3: per-(b,k,pos) corner offsets + bilinear weights ----
__global__ void k_coords(const float* __restrict__ off_ws, int4* __restrict__ G_off,
                         float4* __restrict__ G_w) {
    int t = blockIdx.x * 256 + threadIdx.x;   // 294912 total
    int b = t / 36864;
    int r = t - b * 36864;
    int k = r >> 12;
    int pos = r & 4095;
    int y = pos >> 6, x = pos & 63;
    const float* ow = off_ws + ((size_t)(b << 12) + pos) * 18;
    float dy = ow[2 * k], dx = ow[2 * k + 1];
    float pyf = (float)(y - 1 + k / 3) + dy;
    float pxf = (float)(x - 1 + k % 3) + dx;
    float y0f = floorf(pyf), x0f = floorf(pxf);
    int y0 = (int)y0f, x0 = (int)x0f;
    int y1 = y0 + 1, x1 = x0 + 1;
    float wy1 = pyf - y0f, wy0 = 1.f - wy1;
    float wx1 = pxf - x0f, wx0 = 1.f - wx1;
    bool vy0 = (y0 >= 0) & (y0 < HH), vy1 = (y1 >= 0) & (y1 < HH);
    bool vx0 = (x0 >= 0) & (x0 < WW), vx1 = (x1 >= 0) & (x1 < WW);
    int yc0 = min(max(y0, 0), HH - 1), yc1 = min(max(y1, 0), HH - 1);
    int xc0 = min(max(x0, 0), WW - 1), xc1 = min(max(x1, 0), WW - 1);
    int base = b * HP * HP * CCH;
    int4 go;
    go.x = base + ((yc0 + 1) * HP + (xc0 + 1)) * CCH;
    go.y = base + ((yc0 + 1) * HP + (xc1 + 1)) * CCH;
    go.z = base + ((yc1 + 1) * HP + (xc0 + 1)) * CCH;
    go.w = base + ((yc1 + 1) * HP + (xc1 + 1)) * CCH;
    float4 gw;
    gw.x = (vy0 & vx0) ? wy0 * wx0 : 0.f;
    gw.y = (vy0 & vx1) ? wy0 * wx1 : 0.f;
    gw.z = (vy1 & vx0) ? wy1 * wx0 : 0.f;
    gw.w = (vy1 & vx1) ? wy1 * wx1 : 0.f;
    G_off[t] = go;
    G_w[t] = gw;
}

// ---- K4: main deformable GEMM: 128x128 tile, double-buffered LDS, pipelined gather ----
__global__ __launch_bounds__(256, 2) void k_main(const float* __restrict__ xT,
                                                 const u16* __restrict__ W2r,
                                                 const int4* __restrict__ G_off,
                                                 const float4* __restrict__ G_w,
                                                 const float* __restrict__ bias,
                                                 float* __restrict__ out) {
    __shared__ __align__(16) u16 As[2][128 * 40];
    __shared__ __align__(16) u16 Bs[2][128 * 40];
    int b = blockIdx.z;
    int o0 = blockIdx.y * 128;
    int pos0 = blockIdx.x * 128;
    int t = threadIdx.x, lane = t & 63, wv = t >> 6;
    int wr = wv >> 1, wc = wv & 1;
    int pos_l = t & 127, jp = t >> 7;
    int arow = t >> 1, ah = t & 1;

    f32x4 acc[4][4];
    f32x4 z = {0.f, 0.f, 0.f, 0.f};
#pragma unroll
    for (int i = 0; i < 4; ++i)
#pragma unroll
        for (int j = 0; j < 4; ++j) acc[i][j] = z;

    const u16* Ap = W2r + (size_t)(o0 + arow) * KTOT + ah * 16;   // advance by 32 per k-step
    int gbase = ((b * 9) << 12) + pos0 + pos_l;

    // current / next-k9 coords
    int4 go = G_off[gbase];
    float4 gw = G_w[gbase];
    int4 go_n = go;
    float4 gw_n = gw;

    // ---- prologue: stage k=0 into buf 0 ----
    {
        uint4 a0 = *(const uint4*)(Ap);
        uint4 a1 = *(const uint4*)(Ap + 8);
        int cb = jp * 16;
        const float* p0 = xT + go.x + cb;
        const float* p1 = xT + go.y + cb;
        const float* p2 = xT + go.z + cb;
        const float* p3 = xT + go.w + cb;
        f32x4 cr[16];
#pragma unroll
        for (int s = 0; s < 4; ++s) {
            cr[s]      = *(const f32x4*)(p0 + s * 4);
            cr[4 + s]  = *(const f32x4*)(p1 + s * 4);
            cr[8 + s]  = *(const f32x4*)(p2 + s * 4);
            cr[12 + s] = *(const f32x4*)(p3 + s * 4);
        }
        *(uint4*)&As[0][arow * 40 + ah * 16] = a0;
        *(uint4*)&As[0][arow * 40 + ah * 16 + 8] = a1;
        float vv[16];
#pragma unroll
        for (int s = 0; s < 4; ++s)
#pragma unroll
            for (int e = 0; e < 4; ++e)
                vv[s * 4 + e] = gw.x * cr[s][e] + gw.y * cr[4 + s][e] + gw.z * cr[8 + s][e] + gw.w * cr[12 + s][e];
        uint4 d0, d1;
        d0.x = pk2(vv[0], vv[1]);   d0.y = pk2(vv[2], vv[3]);
        d0.z = pk2(vv[4], vv[5]);   d0.w = pk2(vv[6], vv[7]);
        d1.x = pk2(vv[8], vv[9]);   d1.y = pk2(vv[10], vv[11]);
        d1.z = pk2(vv[12], vv[13]); d1.w = pk2(vv[14], vv[15]);
        *(uint4*)&Bs[0][pos_l * 40 + jp * 16] = d0;
        *(uint4*)&Bs[0][pos_l * 40 + jp * 16 + 8] = d1;
    }
    __syncthreads();

    int buf = 0;
    for (int k9 = 0; k9 < 9; ++k9) {
        if (k9 < 8) {                         // prefetch next tap's coords (used 8 steps later)
            go_n = G_off[gbase + ((k9 + 1) << 12)];
            gw_n = G_w[gbase + ((k9 + 1) << 12)];
        }
#pragma unroll
        for (int cs = 0; cs < 8; ++cs) {
            bool has_next = (k9 < 8) || (cs < 7);
            uint4 a0n, a1n;
            f32x4 cr[16];
            if (has_next) {
                const u16* An = Ap + (k9 * 8 + cs + 1) * 32;
                a0n = *(const uint4*)(An);
                a1n = *(const uint4*)(An + 8);
                int4 g = (cs < 7) ? go : go_n;
                int cb = ((cs < 7) ? (cs + 1) * 32 : 0) + jp * 16;
                const float* p0 = xT + g.x + cb;
                const float* p1 = xT + g.y + cb;
                const float* p2 = xT + g.z + cb;
                const float* p3 = xT + g.w + cb;
#pragma unroll
                for (int s = 0; s < 4; ++s) {
                    cr[s]      = *(const f32x4*)(p0 + s * 4);
                    cr[4 + s]  = *(const f32x4*)(p1 + s * 4);
                    cr[8 + s]  = *(const f32x4*)(p2 + s * 4);
                    cr[12 + s] = *(const f32x4*)(p3 + s * 4);
                }
            }
            // compute current step from buf
            {
                int q = lane >> 4, m = lane & 15;
                short8 af[4], bfr[4];
#pragma unroll
                for (int ao = 0; ao < 4; ++ao)
                    af[ao] = *(const short8*)&As[buf][(wr * 64 + ao * 16 + m) * 40 + q * 8];
#pragma unroll
                for (int bn = 0; bn < 4; ++bn)
                    bfr[bn] = *(const short8*)&Bs[buf][(wc * 64 + bn * 16 + m) * 40 + q * 8];
#pragma unroll
                for (int ao = 0; ao < 4; ++ao)
#pragma unroll
                    for (int bn = 0; bn < 4; ++bn)
                        acc[ao][bn] = __builtin_amdgcn_mfma_f32_16x16x32_bf16(af[ao], bfr[bn], acc[ao][bn], 0, 0, 0);
            }
            if (has_next) {
                float4 g = (cs < 7) ? gw : gw_n;
                float vv[16];
#pragma unroll
                for (int s = 0; s < 4; ++s)
#pragma unroll
                    for (int e = 0; e < 4; ++e)
                        vv[s * 4 + e] = g.x * cr[s][e] + g.y * cr[4 + s][e] + g.z * cr[8 + s][e] + g.w * cr[12 + s][e];
                uint4 d0, d1;
                d0.x = pk2(vv[0], vv[1]);   d0.y = pk2(vv[2], vv[3]);
                d0.z = pk2(vv[4], vv[5]);   d0.w = pk2(vv[6], vv[7]);
                d1.x = pk2(vv[8], vv[9]);   d1.y = pk2(vv[10], vv[11]);
                d1.z = pk2(vv[12], vv[13]); d1.w = pk2(vv[14], vv[15]);
                *(uint4*)&As[buf ^ 1][arow * 40 + ah * 16] = a0n;
                *(uint4*)&As[buf ^ 1][arow * 40 + ah * 16 + 8] = a1n;
                *(uint4*)&Bs[buf ^ 1][pos_l * 40 + jp * 16] = d0;
                *(uint4*)&Bs[buf ^ 1][pos_l * 40 + jp * 16 + 8] = d1;
            }
            __syncthreads();
            buf ^= 1;
        }
        go = go_n;
        gw = gw_n;
    }

    // epilogue: bias + sigmoid -> fp32 NCHW
    int q = lane >> 4, nn = lane & 15;
#pragma unroll
    for (int ao = 0; ao < 4; ++ao) {
        int ob = o0 + wr * 64 + ao * 16 + q * 4;
#pragma unroll
        for (int bn = 0; bn < 4; ++bn) {
            int pos = pos0 + wc * 64 + bn * 16 + nn;
#pragma unroll
            for (int r = 0; r < 4; ++r) {
                float v = acc[ao][bn][r] + bias[ob + r];
                float sg = 1.0f / (1.0f + __expf(-v));
                out[(size_t)((b * CCH + ob + r) * NPOS) + pos] = sg;
            }
        }
    }
}

extern "C" void kernel_launch(void* const* d_in, const int* in_sizes, int n_in,
                              void* d_out, int out_size, void* d_ws, size_t ws_size,
                              hipStream_t stream) {
    if (ws_size < WS_NEED) return;  // insufficient scratch — fail visibly rather than corrupt
    const float* x     = (const float*)d_in[0];
    const float* w_off = (const float*)d_in[1];
    const float* b_off = (const float*)d_in[2];
    const float* w     = (const float*)d_in[3];
    const float* bias  = (const float*)d_in[4];
    float* out = (float*)d_out;

    char* ws = (char*)d_ws;
    float* xT      = (float*)ws;
    u16*   W2r     = (u16*)(ws + W2R_OFF);
    u16*   Woff2   = (u16*)(ws + WOFF2_OFF);
    float* off_ws  = (float*)(ws + OFFWS_OFF);
    int4*  G_off   = (int4*)(ws + GOFF_OFF);
    float4* G_w    = (float4*)(ws + GW_OFF);

    hipMemsetAsync(xT, 0, XT_BYTES, stream);
    k_prep<<<2592, 256, 0, stream>>>(w, w_off, W2r, Woff2);
    k_init<<<2304, 256, 0, stream>>>(b_off, off_ws);
    k_transpose<<<dim3(4, 64, 8), 256, 0, stream>>>(x, xT);
    k_offconv<<<dim3(32, 9, 8), 256, 0, stream>>>(xT, Woff2, off_ws);
    k_coords<<<1152, 256, 0, stream>>>(off_ws, G_off, G_w);
    k_main<<<dim3(32, 2, 8), 256, 0, stream>>>(xT, W2r, G_off, G_w, bias, out);
}

// Round 4
// 343.071 us; speedup vs baseline: 1.5391x; 1.5391x over previous
//
#include <hip/hip_runtime.h>

typedef unsigned short u16;
typedef unsigned int u32;
typedef __attribute__((ext_vector_type(8))) short short8;
typedef __attribute__((ext_vector_type(4))) float f32x4;

#define BB 8
#define CCH 256
#define HH 64
#define WW 64
#define HP 66
#define NPOS 4096
#define KTOT 2304

// ---- ws layout (bytes) ----
#define XT_BYTES   17842176ull                 // bf16 [8][66][66][256]
#define W2R_OFF    17842176ull                 // bf16 [256][2304]
#define WOFF2_OFF  19021824ull                 // bf16 [32][2304]
#define OFFWS_OFF  19169280ull                 // fp32 [8][4096][18]
#define S_OFF      21528576ull                 // bf16 [nb][9][4096][256]
#define S_BATCH    18874368ull                 // bytes per batch

__device__ __forceinline__ float bf2f(u16 u) {
    union { u32 u; float f; } v; v.u = ((u32)u) << 16; return v.f;
}
__device__ __forceinline__ u16 f2bf(float f) {
    union { float f; u32 u; } v; v.f = f;
    u32 r = v.u + 0x7FFFu + ((v.u >> 16) & 1u);
    return (u16)(r >> 16);
}
__device__ __forceinline__ u32 pk2(float a, float b) {
    return (u32)f2bf(a) | ((u32)f2bf(b) << 16);
}
__device__ __forceinline__ void bf2x2(u32 p, float& a, float& b) {
    union { u32 u; float f; } va, vb;
    va.u = p << 16; vb.u = p & 0xffff0000u;
    a = va.f; b = vb.f;
}
// async global->LDS, 16B per lane; LDS dest = uniform base + lane*16
__device__ __forceinline__ void ldg_lds16(const u16* g, u16* l) {
    __builtin_amdgcn_global_load_lds((const __attribute__((address_space(1))) u32*)g,
                                     (__attribute__((address_space(3))) u32*)l, 16, 0, 0);
}

// ---- K0: reorder weights (fp32 -> bf16): W2r[o][k*256+c] = w[o][c][k]; Woff2 32 rows (>=18 zero) ----
__global__ void k_prep(const float* __restrict__ w, const float* __restrict__ w_off,
                       u16* __restrict__ W2r, u16* __restrict__ Woff2) {
    int t = blockIdx.x * 256 + threadIdx.x;
    if (t < CCH * KTOT) {
        int o = t / KTOT, kk = t % KTOT, k = kk >> 8, c = kk & 255;
        W2r[t] = f2bf(w[(o * CCH + c) * 9 + k]);
    } else {
        int u = t - CCH * KTOT;   // u < 32*2304 exactly by grid sizing
        int o = u / KTOT, kk = u % KTOT, k = kk >> 8, c = kk & 255;
        Woff2[u] = (o < 18) ? f2bf(w_off[(o * CCH + c) * 9 + k]) : (u16)0;
    }
}

// ---- K0b: off_ws[b][pos][o] = b_off[o]  (bias init; k_offconv atomically accumulates) ----
__global__ void k_init(const float* __restrict__ b_off, float* __restrict__ off_ws) {
    int t = blockIdx.x * 256 + threadIdx.x;    // 589824 exactly
    off_ws[t] = b_off[t % 18];
}

// ---- K1: transpose+pad fp32 NCHW -> bf16 NHWC padded; borders pre-zeroed by memset ----
__global__ __launch_bounds__(256) void k_transpose(const float* __restrict__ x, u16* __restrict__ xT) {
    __shared__ __align__(16) float T[64][72];
    int b = blockIdx.z, y = blockIdx.y, c0 = blockIdx.x * 64;
    int t = threadIdx.x;
    {
        int i = t >> 2, seg = t & 3;   // channel i, 16-float x-segment
        const float* src = x + (((size_t)(b * CCH + c0 + i) * HH + y) * WW) + seg * 16;
        float4 v0 = *(const float4*)(src);
        float4 v1 = *(const float4*)(src + 4);
        float4 v2 = *(const float4*)(src + 8);
        float4 v3 = *(const float4*)(src + 12);
        *(float4*)&T[i][seg * 16]      = v0;
        *(float4*)&T[i][seg * 16 + 4]  = v1;
        *(float4*)&T[i][seg * 16 + 8]  = v2;
        *(float4*)&T[i][seg * 16 + 12] = v3;
    }
    __syncthreads();
    {
        int xc = t >> 2, cs = t & 3;   // x-position xc, 16-channel segment cs
        u16* dst = xT + (((size_t)(b * HP + y + 1) * HP) + (xc + 1)) * CCH + c0 + cs * 16;
        u32 p[8];
#pragma unroll
        for (int j = 0; j < 8; ++j)
            p[j] = pk2(T[cs * 16 + 2 * j][xc], T[cs * 16 + 2 * j + 1][xc]);
        uint4 d0, d1;
        d0.x = p[0]; d0.y = p[1]; d0.z = p[2]; d0.w = p[3];
        d1.x = p[4]; d1.y = p[5]; d1.z = p[6]; d1.w = p[7];
        *(uint4*)dst = d0;
        *(uint4*)(dst + 8) = d1;
    }
}

// ---- K2: offset conv GEMM, K-split by tap: grid (32 posTiles, 9, 8); global_load_lds staging ----
__global__ __launch_bounds__(256) void k_offconv(const u16* __restrict__ xT,
                                                 const u16* __restrict__ Woff2,
                                                 float* __restrict__ off_ws) {
    __shared__ __align__(16) u16 AS[2][1024];   // [q4][32 row][8c] = 2KB
    __shared__ __align__(16) u16 BS[2][4096];   // [q4][128 row][8c] = 8KB
    int b = blockIdx.z, k9 = blockIdx.y;
    int pos0 = blockIdx.x * 128;
    int ky = k9 / 3, kx = k9 % 3;
    int t = threadIdx.x, lane = t & 63, wv = t >> 6;

    // B staging lane coords: slots s0=t, s1=t+256 -> row=s&127, q=s>>7
    int rB = t & 127, qB = t >> 7;
    int posB = pos0 + rB;
    const u16* pB0 = xT + (((size_t)(b * HP + (posB >> 6) + ky) * HP) + (posB & 63) + kx) * CCH + qB * 8;
    const u16* pB1 = pB0 + 16;   // q+2
    // A staging (t<128): slot s=t -> q=s>>5, row=s&31
    const u16* pA0 = Woff2 + (size_t)(t & 31) * KTOT + k9 * 256 + (t >> 5) * 8;

    f32x4 acc[2][2];
    f32x4 z = {0.f, 0.f, 0.f, 0.f};
    acc[0][0] = z; acc[0][1] = z; acc[1][0] = z; acc[1][1] = z;

    // prologue: stage cs=0 into buf 0
    if (t < 128) ldg_lds16(pA0, &AS[0][wv * 512]);
    ldg_lds16(pB0, &BS[0][wv * 512]);
    ldg_lds16(pB1, &BS[0][2048 + wv * 512]);
    __syncthreads();

    int buf = 0;
    for (int cs = 0; cs < 8; ++cs) {
        if (cs < 7) {
            int d = (cs + 1) * 32;
            if (t < 128) ldg_lds16(pA0 + d, &AS[buf ^ 1][wv * 512]);
            ldg_lds16(pB0 + d, &BS[buf ^ 1][wv * 512]);
            ldg_lds16(pB1 + d, &BS[buf ^ 1][2048 + wv * 512]);
        }
        int q = lane >> 4, m = lane & 15;
        short8 a0 = *(const short8*)&AS[buf][(q * 32 + m) * 8];
        short8 a1 = *(const short8*)&AS[buf][(q * 32 + 16 + m) * 8];
        short8 b0 = *(const short8*)&BS[buf][(q * 128 + wv * 32 + m) * 8];
        short8 b1 = *(const short8*)&BS[buf][(q * 128 + wv * 32 + 16 + m) * 8];
        acc[0][0] = __builtin_amdgcn_mfma_f32_16x16x32_bf16(a0, b0, acc[0][0], 0, 0, 0);
        acc[0][1] = __builtin_amdgcn_mfma_f32_16x16x32_bf16(a0, b1, acc[0][1], 0, 0, 0);
        acc[1][0] = __builtin_amdgcn_mfma_f32_16x16x32_bf16(a1, b0, acc[1][0], 0, 0, 0);
        acc[1][1] = __builtin_amdgcn_mfma_f32_16x16x32_bf16(a1, b1, acc[1][1], 0, 0, 0);
        __syncthreads();
        buf ^= 1;
    }
    int q = lane >> 4, nn = lane & 15;
#pragma unroll
    for (int ao = 0; ao < 2; ++ao)
#pragma unroll
        for (int bn = 0; bn < 2; ++bn) {
            int pos = pos0 + wv * 32 + bn * 16 + nn;
#pragma unroll
            for (int r = 0; r < 4; ++r) {
                int o = ao * 16 + q * 4 + r;
                if (o < 18) {
                    atomicAdd(&off_ws[((size_t)(b << 12) + pos) * 18 + o], acc[ao][bn][r]);
                }
            }
        }
}

// ---- K3: materialize S[bl][k9][pos][c] bf16 via group-coalesced bilinear gather ----
__global__ __launch_bounds__(256) void k_sample(const u16* __restrict__ xT,
                                                const float* __restrict__ off_ws,
                                                u16* __restrict__ S, int b0) {
    int bl = blockIdx.z, b = b0 + bl, k9 = blockIdx.y;
    int pos0 = blockIdx.x * 64;
    int t = threadIdx.x, g = t >> 4, ll = t & 15;
    int ky = k9 / 3, kx = k9 % 3;
    int bbase = b * HP * HP;

    for (int i = 0; i < 4; ++i) {
        int pos = pos0 + g + i * 16;
        int y = pos >> 6, x = pos & 63;
        float2 off = *(const float2*)&off_ws[((size_t)(b << 12) + pos) * 18 + 2 * k9];
        float pyf = (float)(y - 1 + ky) + off.x;
        float pxf = (float)(x - 1 + kx) + off.y;
        float y0f = floorf(pyf), x0f = floorf(pxf);
        int y0 = (int)y0f, x0 = (int)x0f;
        int y1 = y0 + 1, x1 = x0 + 1;
        float wy1 = pyf - y0f, wy0 = 1.f - wy1;
        float wx1 = pxf - x0f, wx0 = 1.f - wx1;
        bool vy0 = (y0 >= 0) & (y0 < HH), vy1 = (y1 >= 0) & (y1 < HH);
        bool vx0 = (x0 >= 0) & (x0 < WW), vx1 = (x1 >= 0) & (x1 < WW);
        int yc0 = min(max(y0, 0), HH - 1), yc1 = min(max(y1, 0), HH - 1);
        int xc0 = min(max(x0, 0), WW - 1), xc1 = min(max(x1, 0), WW - 1);
        float w0 = (vy0 & vx0) ? wy0 * wx0 : 0.f;
        float w1 = (vy0 & vx1) ? wy0 * wx1 : 0.f;
        float w2 = (vy1 & vx0) ? wy1 * wx0 : 0.f;
        float w3 = (vy1 & vx1) ? wy1 * wx1 : 0.f;
        const u16* g0 = xT + (size_t)((bbase + (yc0 + 1) * HP + xc0 + 1)) * CCH;
        const u16* g1 = xT + (size_t)((bbase + (yc0 + 1) * HP + xc1 + 1)) * CCH;
        const u16* g2 = xT + (size_t)((bbase + (yc1 + 1) * HP + xc0 + 1)) * CCH;
        const u16* g3 = xT + (size_t)((bbase + (yc1 + 1) * HP + xc1 + 1)) * CCH;
        u16* sp = S + ((((size_t)(bl * 9 + k9)) << 12) + pos) * CCH;
#pragma unroll
        for (int cp = 0; cp < 4; ++cp) {
            int c = cp * 64 + ll * 4;
            uint2 r0 = *(const uint2*)(g0 + c);
            uint2 r1 = *(const uint2*)(g1 + c);
            uint2 r2 = *(const uint2*)(g2 + c);
            uint2 r3 = *(const uint2*)(g3 + c);
            float f0a, f0b, f0c, f0d, f1a, f1b, f1c, f1d;
            float f2a, f2b, f2c, f2d, f3a, f3b, f3c, f3d;
            bf2x2(r0.x, f0a, f0b); bf2x2(r0.y, f0c, f0d);
            bf2x2(r1.x, f1a, f1b); bf2x2(r1.y, f1c, f1d);
            bf2x2(r2.x, f2a, f2b); bf2x2(r2.y, f2c, f2d);
            bf2x2(r3.x, f3a, f3b); bf2x2(r3.y, f3c, f3d);
            float v0 = w0 * f0a + w1 * f1a + w2 * f2a + w3 * f3a;
            float v1 = w0 * f0b + w1 * f1b + w2 * f2b + w3 * f3b;
            float v2 = w0 * f0c + w1 * f1c + w2 * f2c + w3 * f3c;
            float v3 = w0 * f0d + w1 * f1d + w2 * f2d + w3 * f3d;
            uint2 sv;
            sv.x = pk2(v0, v1); sv.y = pk2(v2, v3);
            *(uint2*)(sp + c) = sv;
        }
    }
}

// ---- K4: GEMM 128x128 tile: A=W2r, B=S, global_load_lds q-swizzled staging, dbuf, sigmoid ----
__global__ __launch_bounds__(256) void k_gemm(const u16* __restrict__ S,
                                              const u16* __restrict__ W2r,
                                              const float* __restrict__ bias,
                                              float* __restrict__ out, int b0) {
    __shared__ __align__(16) u16 AS[2][4096];   // [q4][128 row][8c] = 8KB
    __shared__ __align__(16) u16 BS[2][4096];
    int bl = blockIdx.z, b = b0 + bl;
    int o0 = blockIdx.y * 128;
    int pos0 = blockIdx.x * 128;
    int t = threadIdx.x, lane = t & 63, wv = t >> 6;
    int wr = wv >> 1, wc = wv & 1;

    // staging lane coords: slots s0=t, s1=t+256 -> row=s&127, q=s>>7
    int r0 = t & 127, q0 = t >> 7;
    const u16* pA0 = W2r + (size_t)(o0 + r0) * KTOT + q0 * 8;
    const u16* pA1 = pA0 + 16;
    const u16* pB0 = S + ((((size_t)(bl * 9)) << 12) + pos0 + r0) * CCH + q0 * 8;
    const u16* pB1 = pB0 + 16;

    f32x4 acc[4][4];
    f32x4 z = {0.f, 0.f, 0.f, 0.f};
#pragma unroll
    for (int i = 0; i < 4; ++i)
#pragma unroll
        for (int j = 0; j < 4; ++j) acc[i][j] = z;

    // prologue: stage step 0 (k9=0, cs=0) into buf 0
    ldg_lds16(pA0, &AS[0][wv * 512]);
    ldg_lds16(pA1, &AS[0][2048 + wv * 512]);
    ldg_lds16(pB0, &BS[0][wv * 512]);
    ldg_lds16(pB1, &BS[0][2048 + wv * 512]);
    __syncthreads();

    int buf = 0;
    for (int step = 0; step < 72; ++step) {
        if (step < 71) {
            int ns = step + 1;
            int nk9 = ns >> 3, ncs = ns & 7;
            int offA = nk9 * 256 + ncs * 32;
            size_t offB = (size_t)nk9 * (NPOS * CCH) + ncs * 32;
            ldg_lds16(pA0 + offA, &AS[buf ^ 1][wv * 512]);
            ldg_lds16(pA1 + offA, &AS[buf ^ 1][2048 + wv * 512]);
            ldg_lds16(pB0 + offB, &BS[buf ^ 1][wv * 512]);
            ldg_lds16(pB1 + offB, &BS[buf ^ 1][2048 + wv * 512]);
        }
        int q = lane >> 4, m = lane & 15;
        short8 af[4], bfr[4];
#pragma unroll
        for (int ao = 0; ao < 4; ++ao)
            af[ao] = *(const short8*)&AS[buf][(q * 128 + wr * 64 + ao * 16 + m) * 8];
#pragma unroll
        for (int bn = 0; bn < 4; ++bn)
            bfr[bn] = *(const short8*)&BS[buf][(q * 128 + wc * 64 + bn * 16 + m) * 8];
#pragma unroll
        for (int ao = 0; ao < 4; ++ao)
#pragma unroll
            for (int bn = 0; bn < 4; ++bn)
                acc[ao][bn] = __builtin_amdgcn_mfma_f32_16x16x32_bf16(af[ao], bfr[bn], acc[ao][bn], 0, 0, 0);
        __syncthreads();
        buf ^= 1;
    }

    // epilogue: bias + sigmoid -> fp32 NCHW
    int q = lane >> 4, nn = lane & 15;
#pragma unroll
    for (int ao = 0; ao < 4; ++ao) {
        int ob = o0 + wr * 64 + ao * 16 + q * 4;
#pragma unroll
        for (int bn = 0; bn < 4; ++bn) {
            int pos = pos0 + wc * 64 + bn * 16 + nn;
#pragma unroll
            for (int r = 0; r < 4; ++r) {
                float v = acc[ao][bn][r] + bias[ob + r];
                float sg = 1.0f / (1.0f + __expf(-v));
                out[(size_t)((b * CCH + ob + r) * NPOS) + pos] = sg;
            }
        }
    }
}

extern "C" void kernel_launch(void* const* d_in, const int* in_sizes, int n_in,
                              void* d_out, int out_size, void* d_ws, size_t ws_size,
                              hipStream_t stream) {
    const float* x     = (const float*)d_in[0];
    const float* w_off = (const float*)d_in[1];
    const float* b_off = (const float*)d_in[2];
    const float* w     = (const float*)d_in[3];
    const float* bias  = (const float*)d_in[4];
    float* out = (float*)d_out;

    char* ws = (char*)d_ws;
    u16*   xT      = (u16*)ws;
    u16*   W2r     = (u16*)(ws + W2R_OFF);
    u16*   Woff2   = (u16*)(ws + WOFF2_OFF);
    float* off_ws  = (float*)(ws + OFFWS_OFF);
    u16*   S       = (u16*)(ws + S_OFF);

    // batches per S-pass, adaptive to ws size (correct for any ws >= ~40.5MB)
    int nb = 8;
    while (nb > 1 && ws_size < S_OFF + (size_t)nb * S_BATCH) nb >>= 1;
    if (ws_size < S_OFF + S_BATCH) return;

    hipMemsetAsync(xT, 0, XT_BYTES, stream);
    k_prep<<<2592, 256, 0, stream>>>(w, w_off, W2r, Woff2);
    k_init<<<2304, 256, 0, stream>>>(b_off, off_ws);
    k_transpose<<<dim3(4, 64, 8), 256, 0, stream>>>(x, xT);
    k_offconv<<<dim3(32, 9, 8), 256, 0, stream>>>(xT, Woff2, off_ws);
    for (int p = 0; p < 8; p += nb) {
        k_sample<<<dim3(64, 9, nb), 256, 0, stream>>>(xT, off_ws, S, p);
        k_gemm<<<dim3(32, 2, nb), 256, 0, stream>>>(S, W2r, bias, out, p);
    }
}

// Round 5
// 282.055 us; speedup vs baseline: 1.8720x; 1.2163x over previous
//
#include <hip/hip_runtime.h>

typedef unsigned short u16;
typedef unsigned int u32;
typedef __attribute__((ext_vector_type(8))) short short8;
typedef __attribute__((ext_vector_type(4))) float f32x4;

#define BB 8
#define CCH 256
#define HH 64
#define WW 64
#define HP 66
#define NPOS 4096
#define KTOT 2304

// ---- ws layout (bytes) ----
#define XT_BYTES   17842176ull                 // bf16 [8][66][66][256]
#define W2R_OFF    17842176ull                 // bf16 [256][2304]
#define WOFF2_OFF  19021824ull                 // bf16 [32][2304]
#define P_OFF      19169280ull                 // fp32 [8][9][18][4096] partials
#define OFF2_OFF   40402944ull                 // float2 [8][9][4096]
#define S_OFF      42762240ull                 // bf16 [nb][9][4096][256]
#define S_BATCH    18874368ull                 // bytes per batch

__device__ __forceinline__ float bf2f(u16 u) {
    union { u32 u; float f; } v; v.u = ((u32)u) << 16; return v.f;
}
__device__ __forceinline__ u16 f2bf(float f) {
    union { float f; u32 u; } v; v.f = f;
    u32 r = v.u + 0x7FFFu + ((v.u >> 16) & 1u);
    return (u16)(r >> 16);
}
__device__ __forceinline__ u32 pk2(float a, float b) {
    return (u32)f2bf(a) | ((u32)f2bf(b) << 16);
}
__device__ __forceinline__ void bf2x2(u32 p, float& a, float& b) {
    union { u32 u; float f; } va, vb;
    va.u = p << 16; vb.u = p & 0xffff0000u;
    a = va.f; b = vb.f;
}
// async global->LDS, 16B per lane; LDS dest = wave-uniform base + lane*16
__device__ __forceinline__ void ldg_lds16(const u16* g, u16* l) {
    __builtin_amdgcn_global_load_lds((const __attribute__((address_space(1))) u32*)g,
                                     (__attribute__((address_space(3))) u32*)l, 16, 0, 0);
}

// ---- K0: reorder weights (fp32 -> bf16): W2r[o][k*256+c] = w[o][c][k]; Woff2 32 rows (>=18 zero) ----
__global__ void k_prep(const float* __restrict__ w, const float* __restrict__ w_off,
                       u16* __restrict__ W2r, u16* __restrict__ Woff2) {
    int t = blockIdx.x * 256 + threadIdx.x;
    if (t < CCH * KTOT) {
        int o = t / KTOT, kk = t % KTOT, k = kk >> 8, c = kk & 255;
        W2r[t] = f2bf(w[(o * CCH + c) * 9 + k]);
    } else {
        int u = t - CCH * KTOT;   // u < 32*2304 exactly by grid sizing
        int o = u / KTOT, kk = u % KTOT, k = kk >> 8, c = kk & 255;
        Woff2[u] = (o < 18) ? f2bf(w_off[(o * CCH + c) * 9 + k]) : (u16)0;
    }
}

// ---- K1: transpose+pad fp32 NCHW -> bf16 NHWC padded; x = batch (XCD-pinned) ----
__global__ __launch_bounds__(256) void k_transpose(const float* __restrict__ x, u16* __restrict__ xT) {
    __shared__ __align__(16) float T[64][72];
    int b = blockIdx.x, y = blockIdx.y, c0 = blockIdx.z * 64;
    int t = threadIdx.x;
    {
        int i = t >> 2, seg = t & 3;   // channel i, 16-float x-segment
        const float* src = x + (((size_t)(b * CCH + c0 + i) * HH + y) * WW) + seg * 16;
        float4 v0 = *(const float4*)(src);
        float4 v1 = *(const float4*)(src + 4);
        float4 v2 = *(const float4*)(src + 8);
        float4 v3 = *(const float4*)(src + 12);
        *(float4*)&T[i][seg * 16]      = v0;
        *(float4*)&T[i][seg * 16 + 4]  = v1;
        *(float4*)&T[i][seg * 16 + 8]  = v2;
        *(float4*)&T[i][seg * 16 + 12] = v3;
    }
    __syncthreads();
    {
        int xc = t >> 2, cs = t & 3;   // x-position xc, 16-channel segment cs
        u16* dst = xT + (((size_t)(b * HP + y + 1) * HP) + (xc + 1)) * CCH + c0 + cs * 16;
        u32 p[8];
#pragma unroll
        for (int j = 0; j < 8; ++j)
            p[j] = pk2(T[cs * 16 + 2 * j][xc], T[cs * 16 + 2 * j + 1][xc]);
        uint4 d0, d1;
        d0.x = p[0]; d0.y = p[1]; d0.z = p[2]; d0.w = p[3];
        d1.x = p[4]; d1.y = p[5]; d1.z = p[6]; d1.w = p[7];
        *(uint4*)dst = d0;
        *(uint4*)(dst + 8) = d1;
    }
}

// ---- K2: offset conv GEMM, K-split by tap; partial stores (no atomics); x = batch ----
__global__ __launch_bounds__(256) void k_offconv(const u16* __restrict__ xT,
                                                 const u16* __restrict__ Woff2,
                                                 float* __restrict__ P) {
    __shared__ __align__(16) u16 AS[2][1024];   // [q4][32 row][8c] = 2KB
    __shared__ __align__(16) u16 BS[2][4096];   // [q4][128 row][8c] = 8KB
    int b = blockIdx.x, k9 = blockIdx.y;
    int pos0 = blockIdx.z * 128;
    int ky = k9 / 3, kx = k9 % 3;
    int t = threadIdx.x, lane = t & 63, wv = t >> 6;

    int rB = t & 127, qB = t >> 7;
    int posB = pos0 + rB;
    const u16* pB0 = xT + (((size_t)(b * HP + (posB >> 6) + ky) * HP) + (posB & 63) + kx) * CCH + qB * 8;
    const u16* pB1 = pB0 + 16;   // q+2
    const u16* pA0 = Woff2 + (size_t)(t & 31) * KTOT + k9 * 256 + (t >> 5) * 8;

    f32x4 acc[2][2];
    f32x4 z = {0.f, 0.f, 0.f, 0.f};
    acc[0][0] = z; acc[0][1] = z; acc[1][0] = z; acc[1][1] = z;

    if (t < 128) ldg_lds16(pA0, &AS[0][wv * 512]);
    ldg_lds16(pB0, &BS[0][wv * 512]);
    ldg_lds16(pB1, &BS[0][2048 + wv * 512]);
    __syncthreads();

    int buf = 0;
    for (int cs = 0; cs < 8; ++cs) {
        if (cs < 7) {
            int d = (cs + 1) * 32;
            if (t < 128) ldg_lds16(pA0 + d, &AS[buf ^ 1][wv * 512]);
            ldg_lds16(pB0 + d, &BS[buf ^ 1][wv * 512]);
            ldg_lds16(pB1 + d, &BS[buf ^ 1][2048 + wv * 512]);
        }
        int q = lane >> 4, m = lane & 15;
        short8 a0 = *(const short8*)&AS[buf][(q * 32 + m) * 8];
        short8 a1 = *(const short8*)&AS[buf][(q * 32 + 16 + m) * 8];
        short8 b0 = *(const short8*)&BS[buf][(q * 128 + wv * 32 + m) * 8];
        short8 b1 = *(const short8*)&BS[buf][(q * 128 + wv * 32 + 16 + m) * 8];
        acc[0][0] = __builtin_amdgcn_mfma_f32_16x16x32_bf16(a0, b0, acc[0][0], 0, 0, 0);
        acc[0][1] = __builtin_amdgcn_mfma_f32_16x16x32_bf16(a0, b1, acc[0][1], 0, 0, 0);
        acc[1][0] = __builtin_amdgcn_mfma_f32_16x16x32_bf16(a1, b0, acc[1][0], 0, 0, 0);
        acc[1][1] = __builtin_amdgcn_mfma_f32_16x16x32_bf16(a1, b1, acc[1][1], 0, 0, 0);
        __syncthreads();
        buf ^= 1;
    }
    // coalesced partial stores: P[b][k9][o][pos]
    int q = lane >> 4, nn = lane & 15;
    float* Pp = P + (size_t)(b * 9 + k9) * 18 * NPOS;
#pragma unroll
    for (int ao = 0; ao < 2; ++ao)
#pragma unroll
        for (int bn = 0; bn < 2; ++bn) {
            int pos = pos0 + wv * 32 + bn * 16 + nn;
#pragma unroll
            for (int r = 0; r < 4; ++r) {
                int o = ao * 16 + q * 4 + r;
                if (o < 18) Pp[o * NPOS + pos] = acc[ao][bn][r];
            }
        }
}

// ---- K2b: reduce 9 tap-partials + bias -> off2[b][tap][pos] = (dy,dx) ----
__global__ __launch_bounds__(256) void k_reduce(const float* __restrict__ P,
                                                const float* __restrict__ b_off,
                                                float2* __restrict__ off2) {
    int b = blockIdx.x;
    int pos = blockIdx.y * 256 + threadIdx.x;
    float s[18];
#pragma unroll
    for (int o = 0; o < 18; ++o) s[o] = b_off[o];
    const float* Pp = P + (size_t)(b * 9) * 18 * NPOS + pos;
    for (int k9 = 0; k9 < 9; ++k9) {
#pragma unroll
        for (int o = 0; o < 18; ++o)
            s[o] += Pp[(k9 * 18 + o) * NPOS];
    }
#pragma unroll
    for (int op = 0; op < 9; ++op) {
        float2 v; v.x = s[2 * op]; v.y = s[2 * op + 1];
        off2[(((size_t)(b * 9 + op)) << 12) + pos] = v;
    }
}

// ---- K3: materialize S[bl][k9][pos][c] bf16 via group-coalesced bilinear gather; x = batch ----
__global__ __launch_bounds__(256) void k_sample(const u16* __restrict__ xT,
                                                const float2* __restrict__ off2,
                                                u16* __restrict__ S, int b0) {
    int bl = blockIdx.x, b = b0 + bl, k9 = blockIdx.y;
    int pos0 = blockIdx.z * 64;
    int t = threadIdx.x, g = t >> 4, ll = t & 15;
    int ky = k9 / 3, kx = k9 % 3;
    int bbase = b * HP * HP;

    for (int i = 0; i < 4; ++i) {
        int pos = pos0 + g + i * 16;
        int y = pos >> 6, x = pos & 63;
        float2 off = off2[(((size_t)(b * 9 + k9)) << 12) + pos];
        float pyf = (float)(y - 1 + ky) + off.x;
        float pxf = (float)(x - 1 + kx) + off.y;
        float y0f = floorf(pyf), x0f = floorf(pxf);
        int y0 = (int)y0f, x0 = (int)x0f;
        int y1 = y0 + 1, x1 = x0 + 1;
        float wy1 = pyf - y0f, wy0 = 1.f - wy1;
        float wx1 = pxf - x0f, wx0 = 1.f - wx1;
        bool vy0 = (y0 >= 0) & (y0 < HH), vy1 = (y1 >= 0) & (y1 < HH);
        bool vx0 = (x0 >= 0) & (x0 < WW), vx1 = (x1 >= 0) & (x1 < WW);
        int yc0 = min(max(y0, 0), HH - 1), yc1 = min(max(y1, 0), HH - 1);
        int xc0 = min(max(x0, 0), WW - 1), xc1 = min(max(x1, 0), WW - 1);
        float w0 = (vy0 & vx0) ? wy0 * wx0 : 0.f;
        float w1 = (vy0 & vx1) ? wy0 * wx1 : 0.f;
        float w2 = (vy1 & vx0) ? wy1 * wx0 : 0.f;
        float w3 = (vy1 & vx1) ? wy1 * wx1 : 0.f;
        const u16* g0 = xT + (size_t)((bbase + (yc0 + 1) * HP + xc0 + 1)) * CCH;
        const u16* g1 = xT + (size_t)((bbase + (yc0 + 1) * HP + xc1 + 1)) * CCH;
        const u16* g2 = xT + (size_t)((bbase + (yc1 + 1) * HP + xc0 + 1)) * CCH;
        const u16* g3 = xT + (size_t)((bbase + (yc1 + 1) * HP + xc1 + 1)) * CCH;
        u16* sp = S + ((((size_t)(bl * 9 + k9)) << 12) + pos) * CCH;
#pragma unroll
        for (int cp = 0; cp < 4; ++cp) {
            int c = cp * 64 + ll * 4;
            uint2 r0 = *(const uint2*)(g0 + c);
            uint2 r1 = *(const uint2*)(g1 + c);
            uint2 r2 = *(const uint2*)(g2 + c);
            uint2 r3 = *(const uint2*)(g3 + c);
            float f0a, f0b, f0c, f0d, f1a, f1b, f1c, f1d;
            float f2a, f2b, f2c, f2d, f3a, f3b, f3c, f3d;
            bf2x2(r0.x, f0a, f0b); bf2x2(r0.y, f0c, f0d);
            bf2x2(r1.x, f1a, f1b); bf2x2(r1.y, f1c, f1d);
            bf2x2(r2.x, f2a, f2b); bf2x2(r2.y, f2c, f2d);
            bf2x2(r3.x, f3a, f3b); bf2x2(r3.y, f3c, f3d);
            float v0 = w0 * f0a + w1 * f1a + w2 * f2a + w3 * f3a;
            float v1 = w0 * f0b + w1 * f1b + w2 * f2b + w3 * f3b;
            float v2 = w0 * f0c + w1 * f1c + w2 * f2c + w3 * f3c;
            float v3 = w0 * f0d + w1 * f1d + w2 * f2d + w3 * f3d;
            uint2 sv;
            sv.x = pk2(v0, v1); sv.y = pk2(v2, v3);
            *(uint2*)(sp + c) = sv;
        }
    }
}

// ---- K4: GEMM 128x128 tile, BK=64, global_load_lds dbuf (36 barriers), sigmoid; x = batch ----
__global__ __launch_bounds__(256) void k_gemm(const u16* __restrict__ S,
                                              const u16* __restrict__ W2r,
                                              const float* __restrict__ bias,
                                              float* __restrict__ out, int b0) {
    __shared__ __align__(16) u16 AS[2][8192];   // [q8][128 row][8c] = 16KB
    __shared__ __align__(16) u16 BS[2][8192];
    int bl = blockIdx.x, b = b0 + bl;
    int o0 = blockIdx.y * 128;
    int pos0 = blockIdx.z * 128;
    int t = threadIdx.x, lane = t & 63, wv = t >> 6;
    int wr = wv >> 1, wc = wv & 1;

    int row = t & 127, qh = t >> 7;   // staging: slot s = i*256 + t -> row = t&127, q = 2i + qh
    const u16* pA = W2r + (size_t)(o0 + row) * KTOT + qh * 8;
    const u16* pB = S + ((((size_t)(bl * 9)) << 12) + pos0 + row) * CCH + qh * 8;

    f32x4 acc[4][4];
    f32x4 z = {0.f, 0.f, 0.f, 0.f};
#pragma unroll
    for (int i = 0; i < 4; ++i)
#pragma unroll
        for (int j = 0; j < 4; ++j) acc[i][j] = z;

    // prologue: stage step 0 (k9=0, c0=0) into buf 0
#pragma unroll
    for (int i = 0; i < 4; ++i) {
        ldg_lds16(pA + i * 16, &AS[0][(i * 256 + wv * 64) * 8]);
        ldg_lds16(pB + i * 16, &BS[0][(i * 256 + wv * 64) * 8]);
    }
    __syncthreads();

    int buf = 0;
    for (int step = 0; step < 36; ++step) {
        if (step < 35) {
            int ns = step + 1;
            int offA = (ns >> 2) * 256 + (ns & 3) * 64;
            size_t offB = (size_t)(ns >> 2) * (NPOS * CCH) + (ns & 3) * 64;
#pragma unroll
            for (int i = 0; i < 4; ++i) {
                ldg_lds16(pA + offA + i * 16, &AS[buf ^ 1][(i * 256 + wv * 64) * 8]);
                ldg_lds16(pB + offB + i * 16, &BS[buf ^ 1][(i * 256 + wv * 64) * 8]);
            }
        }
        int q = lane >> 4, m = lane & 15;
#pragma unroll
        for (int j = 0; j < 2; ++j) {
            short8 af[4], bfr[4];
#pragma unroll
            for (int ao = 0; ao < 4; ++ao)
                af[ao] = *(const short8*)&AS[buf][((j * 4 + q) * 128 + wr * 64 + ao * 16 + m) * 8];
#pragma unroll
            for (int bn = 0; bn < 4; ++bn)
                bfr[bn] = *(const short8*)&BS[buf][((j * 4 + q) * 128 + wc * 64 + bn * 16 + m) * 8];
#pragma unroll
            for (int ao = 0; ao < 4; ++ao)
#pragma unroll
                for (int bn = 0; bn < 4; ++bn)
                    acc[ao][bn] = __builtin_amdgcn_mfma_f32_16x16x32_bf16(af[ao], bfr[bn], acc[ao][bn], 0, 0, 0);
        }
        __syncthreads();
        buf ^= 1;
    }

    // epilogue: bias + sigmoid -> fp32 NCHW
    int q = lane >> 4, nn = lane & 15;
#pragma unroll
    for (int ao = 0; ao < 4; ++ao) {
        int ob = o0 + wr * 64 + ao * 16 + q * 4;
#pragma unroll
        for (int bn = 0; bn < 4; ++bn) {
            int pos = pos0 + wc * 64 + bn * 16 + nn;
#pragma unroll
            for (int r = 0; r < 4; ++r) {
                float v = acc[ao][bn][r] + bias[ob + r];
                float sg = 1.0f / (1.0f + __expf(-v));
                out[(size_t)((b * CCH + ob + r) * NPOS) + pos] = sg;
            }
        }
    }
}

extern "C" void kernel_launch(void* const* d_in, const int* in_sizes, int n_in,
                              void* d_out, int out_size, void* d_ws, size_t ws_size,
                              hipStream_t stream) {
    const float* x     = (const float*)d_in[0];
    const float* w_off = (const float*)d_in[1];
    const float* b_off = (const float*)d_in[2];
    const float* w     = (const float*)d_in[3];
    const float* bias  = (const float*)d_in[4];
    float* out = (float*)d_out;

    char* ws = (char*)d_ws;
    u16*    xT    = (u16*)ws;
    u16*    W2r   = (u16*)(ws + W2R_OFF);
    u16*    Woff2 = (u16*)(ws + WOFF2_OFF);
    float*  P     = (float*)(ws + P_OFF);
    float2* off2  = (float2*)(ws + OFF2_OFF);
    u16*    S     = (u16*)(ws + S_OFF);

    // batches per S-pass, adaptive to ws size
    int nb = 8;
    while (nb > 1 && ws_size < S_OFF + (size_t)nb * S_BATCH) nb >>= 1;
    if (ws_size < S_OFF + S_BATCH) return;

    hipMemsetAsync(xT, 0, XT_BYTES, stream);
    k_prep<<<2592, 256, 0, stream>>>(w, w_off, W2r, Woff2);
    k_transpose<<<dim3(8, 64, 4), 256, 0, stream>>>(x, xT);
    k_offconv<<<dim3(8, 9, 32), 256, 0, stream>>>(xT, Woff2, P);
    k_reduce<<<dim3(8, 16), 256, 0, stream>>>(P, b_off, off2);
    for (int p = 0; p < 8; p += nb) {
        k_sample<<<dim3(nb, 9, 64), 256, 0, stream>>>(xT, off2, S, p);
        k_gemm<<<dim3(nb, 2, 32), 256, 0, stream>>>(S, W2r, bias, out, p);
    }
}